// Round 1
// baseline (1500.418 us; speedup 1.0000x reference)
//
#include <hip/hip_runtime.h>
#include <hip/hip_bf16.h>
#include <math.h>

#define N_NODES 50000
#define N_EDGES 800000
#define N_GRAPHS 64
#define IN_DIM 128
#define HID 64
#define HEADS 4
#define LAT 32

// ---------------------------------------------------------------------------
// Counting-sort of edges by dst: histogram -> exclusive scan -> scatter
// ---------------------------------------------------------------------------
__global__ __launch_bounds__(256) void deg_kernel(const int* __restrict__ dsts,
                                                  int* __restrict__ cnt, int E) {
    int e = blockIdx.x * 256 + threadIdx.x;
    if (e < E) atomicAdd(&cnt[dsts[e]], 1);
}

__global__ __launch_bounds__(1024) void scan_kernel(int* __restrict__ cnt,
                                                    int* __restrict__ offs, int n) {
    __shared__ int buf[1024];
    __shared__ int carryS;
    int t = threadIdx.x;
    if (t == 0) carryS = 0;
    __syncthreads();
    for (int base = 0; base < n; base += 1024) {
        int i = base + t;
        int v = (i < n) ? cnt[i] : 0;
        if (i < n) cnt[i] = 0;   // zero for reuse as scatter counter
        buf[t] = v;
        __syncthreads();
        #pragma unroll
        for (int off = 1; off < 1024; off <<= 1) {
            int tmp = (t >= off) ? buf[t - off] : 0;
            __syncthreads();
            buf[t] += tmp;
            __syncthreads();
        }
        int carry = carryS;
        if (i < n) offs[i] = carry + buf[t] - v;   // exclusive prefix
        __syncthreads();
        if (t == 1023) carryS = carry + buf[1023];
        __syncthreads();
    }
    if (t == 0) offs[n] = carryS;
}

__global__ __launch_bounds__(256) void scatter_kernel(const int* __restrict__ srcs,
                                                      const int* __restrict__ dsts,
                                                      const int* __restrict__ offs,
                                                      int* __restrict__ cnt,
                                                      int* __restrict__ es, int E) {
    int e = blockIdx.x * 256 + threadIdx.x;
    if (e < E) {
        int d = dsts[e];
        int pos = offs[d] + atomicAdd(&cnt[d], 1);
        es[pos] = srcs[e];
    }
}

// ---------------------------------------------------------------------------
// GEMM: C[n,256] = A[n,K] @ W[K,256], fp32. 32 rows/block, 1 col/thread.
// ---------------------------------------------------------------------------
template <int K>
__global__ __launch_bounds__(256) void gemm_kernel(const float* __restrict__ A,
                                                   const float* __restrict__ W,
                                                   float* __restrict__ C, int n) {
    __shared__ float As[32 * K];
    int block_row = blockIdx.x * 32;
    int t = threadIdx.x;
    for (int i = t; i < 32 * K; i += 256) {
        int r = i / K, k = i % K;
        int row = block_row + r;
        As[i] = (row < n) ? A[row * K + k] : 0.f;
    }
    __syncthreads();
    float acc[32];
    #pragma unroll
    for (int r = 0; r < 32; ++r) acc[r] = 0.f;
    int c = t;
    for (int k = 0; k < K; k += 4) {
        float w0 = W[(k + 0) * 256 + c];
        float w1 = W[(k + 1) * 256 + c];
        float w2 = W[(k + 2) * 256 + c];
        float w3 = W[(k + 3) * 256 + c];
        #pragma unroll
        for (int r = 0; r < 32; ++r) {
            float4 a = *reinterpret_cast<const float4*>(&As[r * K + k]);
            acc[r] += a.x * w0 + a.y * w1 + a.z * w2 + a.w * w3;
        }
    }
    for (int r = 0; r < 32; ++r) {
        int row = block_row + r;
        if (row < n) C[row * 256 + c] = acc[r];
    }
}

// ---------------------------------------------------------------------------
// Per-node online-softmax attention. One 256-thread block per dst node.
// thread t: head h = t>>6, dim d = t&63. 64-lane butterfly for logits.
// ---------------------------------------------------------------------------
__global__ __launch_bounds__(256) void attn_kernel(const float* __restrict__ xl,
                                                   const float* __restrict__ xr,
                                                   const int* __restrict__ es,
                                                   const int* __restrict__ offs,
                                                   const float* __restrict__ att,
                                                   const float* __restrict__ bias,
                                                   float* __restrict__ hout, int n) {
    int node = blockIdx.x;
    int t = threadIdx.x;
    int h = t >> 6, d = t & 63;
    int beg = offs[node], end = offs[node + 1];
    float xr_v = xr[node * 256 + t];
    float att_v = att[h * 64 + d];
    float m = -INFINITY, l = 0.f, acc = 0.f;
    for (int i = beg; i < end; ++i) {
        int s = es[i];
        float xlv = xl[s * 256 + t];
        float e = xlv + xr_v;
        e = (e > 0.f) ? e : 0.2f * e;
        float z = e * att_v;
        #pragma unroll
        for (int off = 1; off < 64; off <<= 1) z += __shfl_xor(z, off, 64);
        float mn = fmaxf(m, z);
        float scale = __expf(m - mn);     // first iter: exp(-inf)=0
        float p = __expf(z - mn);
        acc = acc * scale + p * xlv;
        l = l * scale + p;
        m = mn;
    }
    __shared__ float sacc[HEADS][HID];
    sacc[h][d] = acc / (l + 1e-16f);
    __syncthreads();
    if (t < HID) {
        float v = 0.25f * (sacc[0][t] + sacc[1][t] + sacc[2][t] + sacc[3][t]) + bias[t];
        v = (v > 0.f) ? v : 0.1f * v;
        hout[node * HID + t] = v;
    }
}

// ---------------------------------------------------------------------------
// Pool: pooled[g,d] += h[n,d] for batch[n]==g
// ---------------------------------------------------------------------------
__global__ __launch_bounds__(256) void pool_kernel(const float* __restrict__ hfin,
                                                   const int* __restrict__ batch,
                                                   float* __restrict__ pooled, int n) {
    int i = blockIdx.x * 256 + threadIdx.x;
    if (i < n * HID) {
        int node = i >> 6, d = i & 63;
        atomicAdd(&pooled[batch[node] * HID + d], hfin[i]);
    }
}

// ---------------------------------------------------------------------------
// BN over graphs (biased var) + FC. Single block.
// ---------------------------------------------------------------------------
__global__ __launch_bounds__(256) void final_kernel(const float* __restrict__ pooled,
                                                    const float* __restrict__ gamma,
                                                    const float* __restrict__ beta,
                                                    const float* __restrict__ fcW,
                                                    const float* __restrict__ fcb,
                                                    float* __restrict__ out) {
    __shared__ float P[N_GRAPHS * HID];
    __shared__ float normS[N_GRAPHS * HID];
    __shared__ float meanS[HID], rstdS[HID];
    int t = threadIdx.x;
    for (int i = t; i < N_GRAPHS * HID; i += 256) P[i] = pooled[i];
    __syncthreads();
    if (t < HID) {
        float s = 0.f;
        for (int g = 0; g < N_GRAPHS; ++g) s += P[g * HID + t];
        float mean = s / (float)N_GRAPHS;
        float v = 0.f;
        for (int g = 0; g < N_GRAPHS; ++g) {
            float dd = P[g * HID + t] - mean;
            v += dd * dd;
        }
        v /= (float)N_GRAPHS;
        meanS[t] = mean;
        rstdS[t] = rsqrtf(v + 1e-5f);
    }
    __syncthreads();
    for (int i = t; i < N_GRAPHS * HID; i += 256) {
        int d = i & 63;
        normS[i] = (P[i] - meanS[d]) * rstdS[d] * gamma[d] + beta[d];
    }
    __syncthreads();
    for (int i = t; i < N_GRAPHS * LAT; i += 256) {
        int g = i >> 5, lat = i & 31;
        float s = fcb[lat];
        for (int d = 0; d < HID; ++d) s += normS[g * HID + d] * fcW[lat * HID + d];
        out[i] = s;
    }
}

// ---------------------------------------------------------------------------
extern "C" void kernel_launch(void* const* d_in, const int* in_sizes, int n_in,
                              void* d_out, int out_size, void* d_ws, size_t ws_size,
                              hipStream_t stream) {
    const float* x      = (const float*)d_in[0];
    const int*   ei     = (const int*)d_in[1];
    const int*   batch  = (const int*)d_in[2];
    const float* Wl[3]  = {(const float*)d_in[3], (const float*)d_in[7],  (const float*)d_in[11]};
    const float* Wr[3]  = {(const float*)d_in[4], (const float*)d_in[8],  (const float*)d_in[12]};
    const float* att[3] = {(const float*)d_in[5], (const float*)d_in[9],  (const float*)d_in[13]};
    const float* bia[3] = {(const float*)d_in[6], (const float*)d_in[10], (const float*)d_in[14]};
    const float* gamma  = (const float*)d_in[15];
    const float* beta   = (const float*)d_in[16];
    const float* fcW    = (const float*)d_in[17];
    const float* fcb    = (const float*)d_in[18];
    float* out = (float*)d_out;

    char* p = (char*)d_ws;
    auto alloc = [&](size_t bytes) {
        char* r = p;
        p += (bytes + 255) & ~(size_t)255;
        return r;
    };
    float* xl     = (float*)alloc((size_t)N_NODES * 256 * 4);
    float* xr     = (float*)alloc((size_t)N_NODES * 256 * 4);
    float* hA     = (float*)alloc((size_t)N_NODES * HID * 4);
    float* hB     = (float*)alloc((size_t)N_NODES * HID * 4);
    int*   es     = (int*)alloc((size_t)N_EDGES * 4);
    int*   offs   = (int*)alloc((size_t)(N_NODES + 1) * 4);
    int*   cnt    = (int*)alloc((size_t)N_NODES * 4);
    float* pooled = (float*)alloc((size_t)N_GRAPHS * HID * 4);

    const int* srcs = ei;
    const int* dsts = ei + N_EDGES;

    // --- sort edges by dst (counting sort) ---
    hipMemsetAsync(cnt, 0, (size_t)N_NODES * 4, stream);
    int eb = (N_EDGES + 255) / 256;
    deg_kernel<<<eb, 256, 0, stream>>>(dsts, cnt, N_EDGES);
    scan_kernel<<<1, 1024, 0, stream>>>(cnt, offs, N_NODES);
    scatter_kernel<<<eb, 256, 0, stream>>>(srcs, dsts, offs, cnt, es, N_EDGES);

    // --- 3 GATv2 layers ---
    int gemm_blocks = (N_NODES + 31) / 32;
    const float* hin = x;
    float* houts[3] = {hA, hB, hA};
    for (int l = 0; l < 3; ++l) {
        if (l == 0) {
            gemm_kernel<IN_DIM><<<gemm_blocks, 256, 0, stream>>>(hin, Wl[l], xl, N_NODES);
            gemm_kernel<IN_DIM><<<gemm_blocks, 256, 0, stream>>>(hin, Wr[l], xr, N_NODES);
        } else {
            gemm_kernel<HID><<<gemm_blocks, 256, 0, stream>>>(hin, Wl[l], xl, N_NODES);
            gemm_kernel<HID><<<gemm_blocks, 256, 0, stream>>>(hin, Wr[l], xr, N_NODES);
        }
        attn_kernel<<<N_NODES, 256, 0, stream>>>(xl, xr, es, offs, att[l], bia[l],
                                                 houts[l], N_NODES);
        hin = houts[l];
    }

    // --- pool + BN + FC ---
    hipMemsetAsync(pooled, 0, (size_t)N_GRAPHS * HID * 4, stream);
    int pb = (N_NODES * HID + 255) / 256;
    pool_kernel<<<pb, 256, 0, stream>>>(hin, batch, pooled, N_NODES);
    final_kernel<<<1, 256, 0, stream>>>(pooled, gamma, beta, fcW, fcb, out);
}

// Round 2
// 854.950 us; speedup vs baseline: 1.7550x; 1.7550x over previous
//
#include <hip/hip_runtime.h>
#include <hip/hip_bf16.h>
#include <math.h>

#define N_NODES 50000
#define N_EDGES 800000
#define N_GRAPHS 64
#define IN_DIM 128
#define HID 64
#define HEADS 4
#define LAT 32
#define SCAN_BLOCKS ((N_NODES + 255) / 256)   // 196

__device__ inline unsigned short f2bf(float f) {   // RNE
    unsigned u = __float_as_uint(f);
    return (unsigned short)((u + 0x7fffu + ((u >> 16) & 1u)) >> 16);
}

// ---------------------------------------------------------------------------
// Counting-sort of edges by dst: histogram -> hierarchical scan -> scatter
// ---------------------------------------------------------------------------
__global__ __launch_bounds__(256) void deg_kernel(const int* __restrict__ dsts,
                                                  int* __restrict__ cnt, int E) {
    int e = blockIdx.x * 256 + threadIdx.x;
    if (e < E) atomicAdd(&cnt[dsts[e]], 1);
}

__global__ __launch_bounds__(256) void sum_kernel(const int* __restrict__ cnt,
                                                  int* __restrict__ bsum) {
    __shared__ int s[256];
    int i = blockIdx.x * 256 + threadIdx.x;
    s[threadIdx.x] = (i < N_NODES) ? cnt[i] : 0;
    __syncthreads();
    for (int off = 128; off; off >>= 1) {
        if (threadIdx.x < off) s[threadIdx.x] += s[threadIdx.x + off];
        __syncthreads();
    }
    if (threadIdx.x == 0) bsum[blockIdx.x] = s[0];
}

__global__ __launch_bounds__(256) void scan_blocks_kernel(const int* __restrict__ bsum,
                                                          int* __restrict__ boffs,
                                                          int* __restrict__ offs_end) {
    __shared__ int buf[256];
    int t = threadIdx.x;
    int v = (t < SCAN_BLOCKS) ? bsum[t] : 0;
    buf[t] = v;
    __syncthreads();
    #pragma unroll
    for (int off = 1; off < 256; off <<= 1) {
        int tmp = (t >= off) ? buf[t - off] : 0;
        __syncthreads();
        buf[t] += tmp;
        __syncthreads();
    }
    if (t < SCAN_BLOCKS) boffs[t] = buf[t] - v;
    if (t == 255) *offs_end = buf[255];
}

__global__ __launch_bounds__(256) void scan_final_kernel(int* __restrict__ cnt,
                                                         const int* __restrict__ boffs,
                                                         int* __restrict__ offs) {
    __shared__ int buf[256];
    int t = threadIdx.x;
    int i = blockIdx.x * 256 + t;
    int v = (i < N_NODES) ? cnt[i] : 0;
    if (i < N_NODES) cnt[i] = 0;   // zero for reuse as scatter counter
    buf[t] = v;
    __syncthreads();
    #pragma unroll
    for (int off = 1; off < 256; off <<= 1) {
        int tmp = (t >= off) ? buf[t - off] : 0;
        __syncthreads();
        buf[t] += tmp;
        __syncthreads();
    }
    if (i < N_NODES) offs[i] = boffs[blockIdx.x] + buf[t] - v;   // exclusive
}

__global__ __launch_bounds__(256) void scatter_kernel(const int* __restrict__ srcs,
                                                      const int* __restrict__ dsts,
                                                      const int* __restrict__ offs,
                                                      int* __restrict__ cnt,
                                                      int* __restrict__ es, int E) {
    int e = blockIdx.x * 256 + threadIdx.x;
    if (e < E) {
        int d = dsts[e];
        int pos = offs[d] + atomicAdd(&cnt[d], 1);
        es[pos] = srcs[e];
    }
}

// ---------------------------------------------------------------------------
// GEMM: C[n,256] = A[n,K] @ W[K,256]. 32 rows/block; thread = 4 cols x 8 rows
// so each ds_read_b128 of A feeds 16 FMAs. Output fp32 or packed bf16.
// ---------------------------------------------------------------------------
template <int K, bool BF16OUT>
__global__ __launch_bounds__(256) void gemm_kernel(const float* __restrict__ A,
                                                   const float* __restrict__ W,
                                                   void* __restrict__ C, int n) {
    __shared__ float As[32 * K];
    int br = blockIdx.x * 32;
    int t = threadIdx.x;
    for (int i = t * 4; i < 32 * K; i += 1024) {
        int r = i / K, k = i % K;
        int row = br + r;
        float4 a = (row < n) ? *reinterpret_cast<const float4*>(&A[(size_t)row * K + k])
                             : make_float4(0.f, 0.f, 0.f, 0.f);
        *reinterpret_cast<float4*>(&As[i]) = a;
    }
    __syncthreads();
    int cg = t & 63;    // cols 4*cg .. 4*cg+3
    int rg = t >> 6;    // rows rg*8 .. rg*8+7
    float acc[8][4];
    #pragma unroll
    for (int r = 0; r < 8; ++r)
        #pragma unroll
        for (int c = 0; c < 4; ++c) acc[r][c] = 0.f;

    for (int k = 0; k < K; k += 4) {
        float4 w0 = *reinterpret_cast<const float4*>(&W[(k + 0) * 256 + 4 * cg]);
        float4 w1 = *reinterpret_cast<const float4*>(&W[(k + 1) * 256 + 4 * cg]);
        float4 w2 = *reinterpret_cast<const float4*>(&W[(k + 2) * 256 + 4 * cg]);
        float4 w3 = *reinterpret_cast<const float4*>(&W[(k + 3) * 256 + 4 * cg]);
        #pragma unroll
        for (int r = 0; r < 8; ++r) {
            float4 a = *reinterpret_cast<const float4*>(&As[(rg * 8 + r) * K + k]);
            acc[r][0] += a.x * w0.x + a.y * w1.x + a.z * w2.x + a.w * w3.x;
            acc[r][1] += a.x * w0.y + a.y * w1.y + a.z * w2.y + a.w * w3.y;
            acc[r][2] += a.x * w0.z + a.y * w1.z + a.z * w2.z + a.w * w3.z;
            acc[r][3] += a.x * w0.w + a.y * w1.w + a.z * w2.w + a.w * w3.w;
        }
    }
    #pragma unroll
    for (int r = 0; r < 8; ++r) {
        int row = br + rg * 8 + r;
        if (row >= n) continue;
        if (BF16OUT) {
            unsigned short b0 = f2bf(acc[r][0]), b1 = f2bf(acc[r][1]);
            unsigned short b2 = f2bf(acc[r][2]), b3 = f2bf(acc[r][3]);
            uint2 pk;
            pk.x = (unsigned)b0 | ((unsigned)b1 << 16);
            pk.y = (unsigned)b2 | ((unsigned)b3 << 16);
            *reinterpret_cast<uint2*>((char*)C + (size_t)row * 512 + 8 * cg) = pk;
        } else {
            float4 v = make_float4(acc[r][0], acc[r][1], acc[r][2], acc[r][3]);
            *reinterpret_cast<float4*>((float*)C + (size_t)row * 256 + 4 * cg) = v;
        }
    }
}

// ---------------------------------------------------------------------------
// Per-node online-softmax attention. 128 threads/node: thread t owns
// head h = t>>5, dims d0 = 2*(t&31), d0+1. Logit reduce = 5-level shfl
// within 32-lane groups. xl gathered as packed bf16 (4 B/lane/edge).
// ---------------------------------------------------------------------------
__global__ __launch_bounds__(128) void attn_kernel(const unsigned* __restrict__ xlp,
                                                   const float2* __restrict__ xr2,
                                                   const int* __restrict__ es,
                                                   const int* __restrict__ offs,
                                                   const float2* __restrict__ att2,
                                                   const float* __restrict__ bias,
                                                   float* __restrict__ hout) {
    int node = blockIdx.x;
    int t = threadIdx.x;                 // 0..127
    int beg = offs[node], end = offs[node + 1];
    float2 xr_v = xr2[(size_t)node * 128 + t];
    float2 att_v = att2[t];
    float m = -INFINITY, l = 0.f, acc0 = 0.f, acc1 = 0.f;
    for (int i = beg; i < end; ++i) {
        int s = es[i];
        unsigned v = xlp[(size_t)s * 128 + t];
        float x0 = __uint_as_float(v << 16);
        float x1 = __uint_as_float(v & 0xffff0000u);
        float e0 = x0 + xr_v.x; e0 = (e0 > 0.f) ? e0 : 0.2f * e0;
        float e1 = x1 + xr_v.y; e1 = (e1 > 0.f) ? e1 : 0.2f * e1;
        float z = e0 * att_v.x + e1 * att_v.y;
        z += __shfl_xor(z, 16);
        z += __shfl_xor(z, 8);
        z += __shfl_xor(z, 4);
        z += __shfl_xor(z, 2);
        z += __shfl_xor(z, 1);
        float mn = fmaxf(m, z);
        float sc = __expf(m - mn);       // first iter: exp(-inf)=0
        float p = __expf(z - mn);
        acc0 = acc0 * sc + p * x0;
        acc1 = acc1 * sc + p * x1;
        l = l * sc + p;
        m = mn;
    }
    __shared__ float sacc[HEADS][HID];
    int h = t >> 5, d0 = (t & 31) * 2;
    float inv = 1.f / (l + 1e-16f);
    sacc[h][d0] = acc0 * inv;
    sacc[h][d0 + 1] = acc1 * inv;
    __syncthreads();
    if (t < HID) {
        float v = 0.25f * (sacc[0][t] + sacc[1][t] + sacc[2][t] + sacc[3][t]) + bias[t];
        v = (v > 0.f) ? v : 0.1f * v;
        hout[(size_t)node * HID + t] = v;
    }
}

// ---------------------------------------------------------------------------
// Pool: batch is sorted -> accumulate runs locally, flush on graph change.
// Block covers 256 nodes; 4 lane-groups of 64 (lane = dim).
// ---------------------------------------------------------------------------
__global__ __launch_bounds__(256) void pool_kernel(const float* __restrict__ hfin,
                                                   const int* __restrict__ batch,
                                                   float* __restrict__ pooled) {
    int base = blockIdx.x * 256;
    int g = threadIdx.x >> 6, lane = threadIdx.x & 63;
    int lim = min(base + 256, N_NODES);
    int cur = -1;
    float s = 0.f;
    for (int i = base + g; i < lim; i += 4) {
        int b = batch[i];
        if (b != cur) {
            if (cur >= 0) atomicAdd(&pooled[cur * HID + lane], s);
            cur = b; s = 0.f;
        }
        s += hfin[(size_t)i * HID + lane];
    }
    if (cur >= 0) atomicAdd(&pooled[cur * HID + lane], s);
}

// ---------------------------------------------------------------------------
// BN over graphs (biased var) + FC. Single block.
// ---------------------------------------------------------------------------
__global__ __launch_bounds__(256) void final_kernel(const float* __restrict__ pooled,
                                                    const float* __restrict__ gamma,
                                                    const float* __restrict__ beta,
                                                    const float* __restrict__ fcW,
                                                    const float* __restrict__ fcb,
                                                    float* __restrict__ out) {
    __shared__ float P[N_GRAPHS * HID];
    __shared__ float normS[N_GRAPHS * HID];
    __shared__ float meanS[HID], rstdS[HID];
    int t = threadIdx.x;
    for (int i = t; i < N_GRAPHS * HID; i += 256) P[i] = pooled[i];
    __syncthreads();
    if (t < HID) {
        float s = 0.f;
        for (int g = 0; g < N_GRAPHS; ++g) s += P[g * HID + t];
        float mean = s / (float)N_GRAPHS;
        float v = 0.f;
        for (int g = 0; g < N_GRAPHS; ++g) {
            float dd = P[g * HID + t] - mean;
            v += dd * dd;
        }
        v /= (float)N_GRAPHS;
        meanS[t] = mean;
        rstdS[t] = rsqrtf(v + 1e-5f);
    }
    __syncthreads();
    for (int i = t; i < N_GRAPHS * HID; i += 256) {
        int d = i & 63;
        normS[i] = (P[i] - meanS[d]) * rstdS[d] * gamma[d] + beta[d];
    }
    __syncthreads();
    for (int i = t; i < N_GRAPHS * LAT; i += 256) {
        int g = i >> 5, lat = i & 31;
        float s = fcb[lat];
        for (int d = 0; d < HID; ++d) s += normS[g * HID + d] * fcW[lat * HID + d];
        out[i] = s;
    }
}

// ---------------------------------------------------------------------------
extern "C" void kernel_launch(void* const* d_in, const int* in_sizes, int n_in,
                              void* d_out, int out_size, void* d_ws, size_t ws_size,
                              hipStream_t stream) {
    const float* x      = (const float*)d_in[0];
    const int*   ei     = (const int*)d_in[1];
    const int*   batch  = (const int*)d_in[2];
    const float* Wl[3]  = {(const float*)d_in[3], (const float*)d_in[7],  (const float*)d_in[11]};
    const float* Wr[3]  = {(const float*)d_in[4], (const float*)d_in[8],  (const float*)d_in[12]};
    const float* att[3] = {(const float*)d_in[5], (const float*)d_in[9],  (const float*)d_in[13]};
    const float* bia[3] = {(const float*)d_in[6], (const float*)d_in[10], (const float*)d_in[14]};
    const float* gamma  = (const float*)d_in[15];
    const float* beta   = (const float*)d_in[16];
    const float* fcW    = (const float*)d_in[17];
    const float* fcb    = (const float*)d_in[18];
    float* out = (float*)d_out;

    char* p = (char*)d_ws;
    auto alloc = [&](size_t bytes) {
        char* r = p;
        p += (bytes + 255) & ~(size_t)255;
        return r;
    };
    unsigned* xlp  = (unsigned*)alloc((size_t)N_NODES * 256 * 2);  // bf16 packed
    float* xr      = (float*)alloc((size_t)N_NODES * 256 * 4);
    float* hA      = (float*)alloc((size_t)N_NODES * HID * 4);
    float* hB      = (float*)alloc((size_t)N_NODES * HID * 4);
    int*   es      = (int*)alloc((size_t)N_EDGES * 4);
    int*   offs    = (int*)alloc((size_t)(N_NODES + 1) * 4);
    int*   cnt     = (int*)alloc((size_t)N_NODES * 4);
    int*   bsum    = (int*)alloc((size_t)SCAN_BLOCKS * 4);
    int*   boffs   = (int*)alloc((size_t)SCAN_BLOCKS * 4);
    float* pooled  = (float*)alloc((size_t)N_GRAPHS * HID * 4);

    const int* srcs = ei;
    const int* dsts = ei + N_EDGES;

    // --- sort edges by dst (counting sort, hierarchical scan) ---
    hipMemsetAsync(cnt, 0, (size_t)N_NODES * 4, stream);
    int eb = (N_EDGES + 255) / 256;
    deg_kernel<<<eb, 256, 0, stream>>>(dsts, cnt, N_EDGES);
    sum_kernel<<<SCAN_BLOCKS, 256, 0, stream>>>(cnt, bsum);
    scan_blocks_kernel<<<1, 256, 0, stream>>>(bsum, boffs, &offs[N_NODES]);
    scan_final_kernel<<<SCAN_BLOCKS, 256, 0, stream>>>(cnt, boffs, offs);
    scatter_kernel<<<eb, 256, 0, stream>>>(srcs, dsts, offs, cnt, es, N_EDGES);

    // --- 3 GATv2 layers ---
    int gemm_blocks = (N_NODES + 31) / 32;
    const float* hin = x;
    float* houts[3] = {hA, hB, hA};
    for (int l = 0; l < 3; ++l) {
        if (l == 0) {
            gemm_kernel<IN_DIM, true ><<<gemm_blocks, 256, 0, stream>>>(hin, Wl[l], xlp, N_NODES);
            gemm_kernel<IN_DIM, false><<<gemm_blocks, 256, 0, stream>>>(hin, Wr[l], xr, N_NODES);
        } else {
            gemm_kernel<HID, true ><<<gemm_blocks, 256, 0, stream>>>(hin, Wl[l], xlp, N_NODES);
            gemm_kernel<HID, false><<<gemm_blocks, 256, 0, stream>>>(hin, Wr[l], xr, N_NODES);
        }
        attn_kernel<<<N_NODES, 128, 0, stream>>>(xlp, (const float2*)xr, es, offs,
                                                 (const float2*)att[l], bia[l], houts[l]);
        hin = houts[l];
    }

    // --- pool + BN + FC ---
    hipMemsetAsync(pooled, 0, (size_t)N_GRAPHS * HID * 4, stream);
    pool_kernel<<<SCAN_BLOCKS, 256, 0, stream>>>(hin, batch, pooled);
    final_kernel<<<1, 256, 0, stream>>>(pooled, gamma, beta, fcW, fcb, out);
}

// Round 3
// 658.163 us; speedup vs baseline: 2.2797x; 1.2990x over previous
//
#include <hip/hip_runtime.h>
#include <hip/hip_bf16.h>
#include <math.h>

#define N_NODES 50000
#define N_EDGES 800000
#define N_GRAPHS 64
#define IN_DIM 128
#define HID 64
#define HEADS 4
#define LAT 32
#define SCAN_BLOCKS ((N_NODES + 255) / 256)   // 196

__device__ inline unsigned short f2bf(float f) {   // RNE
    unsigned u = __float_as_uint(f);
    return (unsigned short)((u + 0x7fffu + ((u >> 16) & 1u)) >> 16);
}

// ---------------------------------------------------------------------------
// Counting-sort of edges by dst: histogram -> hierarchical scan -> scatter
// ---------------------------------------------------------------------------
__global__ __launch_bounds__(256) void deg_kernel(const int* __restrict__ dsts,
                                                  int* __restrict__ cnt, int E) {
    int e = blockIdx.x * 256 + threadIdx.x;
    if (e < E) atomicAdd(&cnt[dsts[e]], 1);
}

__global__ __launch_bounds__(256) void sum_kernel(const int* __restrict__ cnt,
                                                  int* __restrict__ bsum) {
    __shared__ int s[256];
    int i = blockIdx.x * 256 + threadIdx.x;
    s[threadIdx.x] = (i < N_NODES) ? cnt[i] : 0;
    __syncthreads();
    for (int off = 128; off; off >>= 1) {
        if (threadIdx.x < off) s[threadIdx.x] += s[threadIdx.x + off];
        __syncthreads();
    }
    if (threadIdx.x == 0) bsum[blockIdx.x] = s[0];
}

__global__ __launch_bounds__(256) void scan_blocks_kernel(const int* __restrict__ bsum,
                                                          int* __restrict__ boffs,
                                                          int* __restrict__ offs_end) {
    __shared__ int buf[256];
    int t = threadIdx.x;
    int v = (t < SCAN_BLOCKS) ? bsum[t] : 0;
    buf[t] = v;
    __syncthreads();
    #pragma unroll
    for (int off = 1; off < 256; off <<= 1) {
        int tmp = (t >= off) ? buf[t - off] : 0;
        __syncthreads();
        buf[t] += tmp;
        __syncthreads();
    }
    if (t < SCAN_BLOCKS) boffs[t] = buf[t] - v;
    if (t == 255) *offs_end = buf[255];
}

__global__ __launch_bounds__(256) void scan_final_kernel(int* __restrict__ cnt,
                                                         const int* __restrict__ boffs,
                                                         int* __restrict__ offs) {
    __shared__ int buf[256];
    int t = threadIdx.x;
    int i = blockIdx.x * 256 + t;
    int v = (i < N_NODES) ? cnt[i] : 0;
    if (i < N_NODES) cnt[i] = 0;   // zero for reuse as scatter counter
    buf[t] = v;
    __syncthreads();
    #pragma unroll
    for (int off = 1; off < 256; off <<= 1) {
        int tmp = (t >= off) ? buf[t - off] : 0;
        __syncthreads();
        buf[t] += tmp;
        __syncthreads();
    }
    if (i < N_NODES) offs[i] = boffs[blockIdx.x] + buf[t] - v;   // exclusive
}

__global__ __launch_bounds__(256) void scatter_kernel(const int* __restrict__ srcs,
                                                      const int* __restrict__ dsts,
                                                      const int* __restrict__ offs,
                                                      int* __restrict__ cnt,
                                                      int* __restrict__ es, int E) {
    int e = blockIdx.x * 256 + threadIdx.x;
    if (e < E) {
        int d = dsts[e];
        int pos = offs[d] + atomicAdd(&cnt[d], 1);
        es[pos] = srcs[e];
    }
}

// ---------------------------------------------------------------------------
// Fused GEMM: xl[n,256](bf16) = A @ Wl,  xr[n,256](fp32) = A @ Wr.
// 512 threads: waves 0-3 -> Wl half, waves 4-7 -> Wr half, shared A tile.
// Thread = 4 cols x 8 rows.
// ---------------------------------------------------------------------------
template <int K>
__global__ __launch_bounds__(512) void gemm2_kernel(const float* __restrict__ A,
                                                    const float* __restrict__ Wl,
                                                    const float* __restrict__ Wr,
                                                    unsigned* __restrict__ xlp,
                                                    float* __restrict__ xr, int n) {
    __shared__ float As[32 * K];
    int br = blockIdx.x * 32;
    int t = threadIdx.x;   // 0..511
    for (int i = t * 4; i < 32 * K; i += 2048) {
        int r = i / K, k = i % K;
        int row = br + r;
        float4 a = (row < n) ? *reinterpret_cast<const float4*>(&A[(size_t)row * K + k])
                             : make_float4(0.f, 0.f, 0.f, 0.f);
        *reinterpret_cast<float4*>(&As[i]) = a;
    }
    __syncthreads();
    int which = t >> 8;          // 0: Wl -> xlp(bf16), 1: Wr -> xr(fp32)
    int tt = t & 255;
    int cg = tt & 63;            // cols 4*cg .. 4*cg+3
    int rg = tt >> 6;            // rows rg*8 .. rg*8+7
    const float* W = which ? Wr : Wl;
    float acc[8][4];
    #pragma unroll
    for (int r = 0; r < 8; ++r)
        #pragma unroll
        for (int c = 0; c < 4; ++c) acc[r][c] = 0.f;

    for (int k = 0; k < K; k += 4) {
        float4 w0 = *reinterpret_cast<const float4*>(&W[(k + 0) * 256 + 4 * cg]);
        float4 w1 = *reinterpret_cast<const float4*>(&W[(k + 1) * 256 + 4 * cg]);
        float4 w2 = *reinterpret_cast<const float4*>(&W[(k + 2) * 256 + 4 * cg]);
        float4 w3 = *reinterpret_cast<const float4*>(&W[(k + 3) * 256 + 4 * cg]);
        #pragma unroll
        for (int r = 0; r < 8; ++r) {
            float4 a = *reinterpret_cast<const float4*>(&As[(rg * 8 + r) * K + k]);
            acc[r][0] += a.x * w0.x + a.y * w1.x + a.z * w2.x + a.w * w3.x;
            acc[r][1] += a.x * w0.y + a.y * w1.y + a.z * w2.y + a.w * w3.y;
            acc[r][2] += a.x * w0.z + a.y * w1.z + a.z * w2.z + a.w * w3.z;
            acc[r][3] += a.x * w0.w + a.y * w1.w + a.z * w2.w + a.w * w3.w;
        }
    }
    #pragma unroll
    for (int r = 0; r < 8; ++r) {
        int row = br + rg * 8 + r;
        if (row >= n) continue;
        if (which == 0) {
            unsigned short b0 = f2bf(acc[r][0]), b1 = f2bf(acc[r][1]);
            unsigned short b2 = f2bf(acc[r][2]), b3 = f2bf(acc[r][3]);
            uint2 pk;
            pk.x = (unsigned)b0 | ((unsigned)b1 << 16);
            pk.y = (unsigned)b2 | ((unsigned)b3 << 16);
            *reinterpret_cast<uint2*>((char*)xlp + (size_t)row * 512 + 8 * cg) = pk;
        } else {
            float4 v = make_float4(acc[r][0], acc[r][1], acc[r][2], acc[r][3]);
            *reinterpret_cast<float4*>(&xr[(size_t)row * 256 + 4 * cg]) = v;
        }
    }
}

// ---------------------------------------------------------------------------
// Attention: ONE 64-lane wave per node (4 nodes / 256-block).
// lane = h*16 + dq : head h, dims 4*dq..4*dq+3 (one uint2 bf16 load/edge).
// Logit reduce = 4 shfl within 16-lane head group; 2-edge unrolled online
// softmax; head-mean via shfl_xor(16,32). No LDS, no syncthreads.
// ---------------------------------------------------------------------------
__global__ __launch_bounds__(256) void attn_kernel(const uint2* __restrict__ xlp,
                                                   const float4* __restrict__ xr4,
                                                   const int* __restrict__ es,
                                                   const int* __restrict__ offs,
                                                   const float4* __restrict__ att4,
                                                   const float4* __restrict__ bias4,
                                                   float* __restrict__ hout) {
    int node = blockIdx.x * 4 + (threadIdx.x >> 6);
    int lane = threadIdx.x & 63;
    int beg = offs[node], end = offs[node + 1];
    float4 xr_v = xr4[(size_t)node * 64 + lane];
    float4 att_v = att4[lane];
    float m = -INFINITY, l = 0.f;
    float a0 = 0.f, a1 = 0.f, a2 = 0.f, a3 = 0.f;

    for (int cb = beg; cb < end; cb += 64) {
        int nch = min(64, end - cb);
        int eidx = (lane < nch) ? es[cb + lane] : 0;
        int j = 0;
        for (; j + 2 <= nch; j += 2) {
            int s0 = __shfl(eidx, j);
            int s1 = __shfl(eidx, j + 1);
            uint2 v0 = xlp[(size_t)s0 * 64 + lane];
            uint2 v1 = xlp[(size_t)s1 * 64 + lane];
            float x00 = __uint_as_float(v0.x << 16);
            float x01 = __uint_as_float(v0.x & 0xffff0000u);
            float x02 = __uint_as_float(v0.y << 16);
            float x03 = __uint_as_float(v0.y & 0xffff0000u);
            float x10 = __uint_as_float(v1.x << 16);
            float x11 = __uint_as_float(v1.x & 0xffff0000u);
            float x12 = __uint_as_float(v1.y << 16);
            float x13 = __uint_as_float(v1.y & 0xffff0000u);
            float e;
            e = x00 + xr_v.x; e = (e > 0.f) ? e : 0.2f * e; float z0 = e * att_v.x;
            e = x10 + xr_v.x; e = (e > 0.f) ? e : 0.2f * e; float z1 = e * att_v.x;
            e = x01 + xr_v.y; e = (e > 0.f) ? e : 0.2f * e; z0 = fmaf(e, att_v.y, z0);
            e = x11 + xr_v.y; e = (e > 0.f) ? e : 0.2f * e; z1 = fmaf(e, att_v.y, z1);
            e = x02 + xr_v.z; e = (e > 0.f) ? e : 0.2f * e; z0 = fmaf(e, att_v.z, z0);
            e = x12 + xr_v.z; e = (e > 0.f) ? e : 0.2f * e; z1 = fmaf(e, att_v.z, z1);
            e = x03 + xr_v.w; e = (e > 0.f) ? e : 0.2f * e; z0 = fmaf(e, att_v.w, z0);
            e = x13 + xr_v.w; e = (e > 0.f) ? e : 0.2f * e; z1 = fmaf(e, att_v.w, z1);
            z0 += __shfl_xor(z0, 8);  z1 += __shfl_xor(z1, 8);
            z0 += __shfl_xor(z0, 4);  z1 += __shfl_xor(z1, 4);
            z0 += __shfl_xor(z0, 2);  z1 += __shfl_xor(z1, 2);
            z0 += __shfl_xor(z0, 1);  z1 += __shfl_xor(z1, 1);
            float mn = fmaxf(m, fmaxf(z0, z1));
            float sc = __expf(m - mn);       // first pair: exp(-inf)=0
            float p0 = __expf(z0 - mn);
            float p1 = __expf(z1 - mn);
            a0 = a0 * sc + p0 * x00 + p1 * x10;
            a1 = a1 * sc + p0 * x01 + p1 * x11;
            a2 = a2 * sc + p0 * x02 + p1 * x12;
            a3 = a3 * sc + p0 * x03 + p1 * x13;
            l = l * sc + p0 + p1;
            m = mn;
        }
        if (j < nch) {   // odd tail edge
            int s0 = __shfl(eidx, j);
            uint2 v0 = xlp[(size_t)s0 * 64 + lane];
            float x00 = __uint_as_float(v0.x << 16);
            float x01 = __uint_as_float(v0.x & 0xffff0000u);
            float x02 = __uint_as_float(v0.y << 16);
            float x03 = __uint_as_float(v0.y & 0xffff0000u);
            float e;
            e = x00 + xr_v.x; e = (e > 0.f) ? e : 0.2f * e; float z0 = e * att_v.x;
            e = x01 + xr_v.y; e = (e > 0.f) ? e : 0.2f * e; z0 = fmaf(e, att_v.y, z0);
            e = x02 + xr_v.z; e = (e > 0.f) ? e : 0.2f * e; z0 = fmaf(e, att_v.z, z0);
            e = x03 + xr_v.w; e = (e > 0.f) ? e : 0.2f * e; z0 = fmaf(e, att_v.w, z0);
            z0 += __shfl_xor(z0, 8);
            z0 += __shfl_xor(z0, 4);
            z0 += __shfl_xor(z0, 2);
            z0 += __shfl_xor(z0, 1);
            float mn = fmaxf(m, z0);
            float sc = __expf(m - mn);
            float p0 = __expf(z0 - mn);
            a0 = a0 * sc + p0 * x00;
            a1 = a1 * sc + p0 * x01;
            a2 = a2 * sc + p0 * x02;
            a3 = a3 * sc + p0 * x03;
            l = l * sc + p0;
            m = mn;
        }
    }
    float inv = 1.f / (l + 1e-16f);
    a0 *= inv; a1 *= inv; a2 *= inv; a3 *= inv;
    // mean over heads: lanes h*16+dq -> sum across h via xor 16, 32
    a0 += __shfl_xor(a0, 16); a0 += __shfl_xor(a0, 32);
    a1 += __shfl_xor(a1, 16); a1 += __shfl_xor(a1, 32);
    a2 += __shfl_xor(a2, 16); a2 += __shfl_xor(a2, 32);
    a3 += __shfl_xor(a3, 16); a3 += __shfl_xor(a3, 32);
    if (lane < 16) {
        float4 bv = bias4[lane];
        float4 o;
        o.x = 0.25f * a0 + bv.x; o.x = (o.x > 0.f) ? o.x : 0.1f * o.x;
        o.y = 0.25f * a1 + bv.y; o.y = (o.y > 0.f) ? o.y : 0.1f * o.y;
        o.z = 0.25f * a2 + bv.z; o.z = (o.z > 0.f) ? o.z : 0.1f * o.z;
        o.w = 0.25f * a3 + bv.w; o.w = (o.w > 0.f) ? o.w : 0.1f * o.w;
        *reinterpret_cast<float4*>(&hout[(size_t)node * HID + lane * 4]) = o;
    }
}

// ---------------------------------------------------------------------------
// Pool: batch sorted -> accumulate runs locally, flush on graph change.
// ---------------------------------------------------------------------------
__global__ __launch_bounds__(256) void pool_kernel(const float* __restrict__ hfin,
                                                   const int* __restrict__ batch,
                                                   float* __restrict__ pooled) {
    int base = blockIdx.x * 256;
    int g = threadIdx.x >> 6, lane = threadIdx.x & 63;
    int lim = min(base + 256, N_NODES);
    int cur = -1;
    float s = 0.f;
    for (int i = base + g; i < lim; i += 4) {
        int b = batch[i];
        if (b != cur) {
            if (cur >= 0) atomicAdd(&pooled[cur * HID + lane], s);
            cur = b; s = 0.f;
        }
        s += hfin[(size_t)i * HID + lane];
    }
    if (cur >= 0) atomicAdd(&pooled[cur * HID + lane], s);
}

// ---------------------------------------------------------------------------
// BN over graphs (biased var) + FC. Single block.
// ---------------------------------------------------------------------------
__global__ __launch_bounds__(256) void final_kernel(const float* __restrict__ pooled,
                                                    const float* __restrict__ gamma,
                                                    const float* __restrict__ beta,
                                                    const float* __restrict__ fcW,
                                                    const float* __restrict__ fcb,
                                                    float* __restrict__ out) {
    __shared__ float P[N_GRAPHS * HID];
    __shared__ float normS[N_GRAPHS * HID];
    __shared__ float meanS[HID], rstdS[HID];
    int t = threadIdx.x;
    for (int i = t; i < N_GRAPHS * HID; i += 256) P[i] = pooled[i];
    __syncthreads();
    if (t < HID) {
        float s = 0.f;
        for (int g = 0; g < N_GRAPHS; ++g) s += P[g * HID + t];
        float mean = s / (float)N_GRAPHS;
        float v = 0.f;
        for (int g = 0; g < N_GRAPHS; ++g) {
            float dd = P[g * HID + t] - mean;
            v += dd * dd;
        }
        v /= (float)N_GRAPHS;
        meanS[t] = mean;
        rstdS[t] = rsqrtf(v + 1e-5f);
    }
    __syncthreads();
    for (int i = t; i < N_GRAPHS * HID; i += 256) {
        int d = i & 63;
        normS[i] = (P[i] - meanS[d]) * rstdS[d] * gamma[d] + beta[d];
    }
    __syncthreads();
    for (int i = t; i < N_GRAPHS * LAT; i += 256) {
        int g = i >> 5, lat = i & 31;
        float s = fcb[lat];
        for (int d = 0; d < HID; ++d) s += normS[g * HID + d] * fcW[lat * HID + d];
        out[i] = s;
    }
}

// ---------------------------------------------------------------------------
extern "C" void kernel_launch(void* const* d_in, const int* in_sizes, int n_in,
                              void* d_out, int out_size, void* d_ws, size_t ws_size,
                              hipStream_t stream) {
    const float* x      = (const float*)d_in[0];
    const int*   ei     = (const int*)d_in[1];
    const int*   batch  = (const int*)d_in[2];
    const float* Wl[3]  = {(const float*)d_in[3], (const float*)d_in[7],  (const float*)d_in[11]};
    const float* Wr[3]  = {(const float*)d_in[4], (const float*)d_in[8],  (const float*)d_in[12]};
    const float* att[3] = {(const float*)d_in[5], (const float*)d_in[9],  (const float*)d_in[13]};
    const float* bia[3] = {(const float*)d_in[6], (const float*)d_in[10], (const float*)d_in[14]};
    const float* gamma  = (const float*)d_in[15];
    const float* beta   = (const float*)d_in[16];
    const float* fcW    = (const float*)d_in[17];
    const float* fcb    = (const float*)d_in[18];
    float* out = (float*)d_out;

    char* p = (char*)d_ws;
    auto alloc = [&](size_t bytes) {
        char* r = p;
        p += (bytes + 255) & ~(size_t)255;
        return r;
    };
    unsigned* xlp  = (unsigned*)alloc((size_t)N_NODES * 256 * 2);  // bf16 packed
    float* xr      = (float*)alloc((size_t)N_NODES * 256 * 4);
    float* hA      = (float*)alloc((size_t)N_NODES * HID * 4);
    float* hB      = (float*)alloc((size_t)N_NODES * HID * 4);
    int*   es      = (int*)alloc((size_t)N_EDGES * 4);
    int*   offs    = (int*)alloc((size_t)(N_NODES + 1) * 4);
    int*   cnt     = (int*)alloc((size_t)N_NODES * 4);
    int*   bsum    = (int*)alloc((size_t)SCAN_BLOCKS * 4);
    int*   boffs   = (int*)alloc((size_t)SCAN_BLOCKS * 4);
    float* pooled  = (float*)alloc((size_t)N_GRAPHS * HID * 4);

    const int* srcs = ei;
    const int* dsts = ei + N_EDGES;

    // --- sort edges by dst (counting sort, hierarchical scan) ---
    hipMemsetAsync(cnt, 0, (size_t)N_NODES * 4, stream);
    int eb = (N_EDGES + 255) / 256;
    deg_kernel<<<eb, 256, 0, stream>>>(dsts, cnt, N_EDGES);
    sum_kernel<<<SCAN_BLOCKS, 256, 0, stream>>>(cnt, bsum);
    scan_blocks_kernel<<<1, 256, 0, stream>>>(bsum, boffs, &offs[N_NODES]);
    scan_final_kernel<<<SCAN_BLOCKS, 256, 0, stream>>>(cnt, boffs, offs);
    scatter_kernel<<<eb, 256, 0, stream>>>(srcs, dsts, offs, cnt, es, N_EDGES);

    // --- 3 GATv2 layers ---
    int gemm_blocks = (N_NODES + 31) / 32;
    const float* hin = x;
    float* houts[3] = {hA, hB, hA};
    for (int l = 0; l < 3; ++l) {
        if (l == 0) {
            gemm2_kernel<IN_DIM><<<gemm_blocks, 512, 0, stream>>>(hin, Wl[l], Wr[l],
                                                                  xlp, xr, N_NODES);
        } else {
            gemm2_kernel<HID><<<gemm_blocks, 512, 0, stream>>>(hin, Wl[l], Wr[l],
                                                               xlp, xr, N_NODES);
        }
        attn_kernel<<<N_NODES / 4, 256, 0, stream>>>((const uint2*)xlp, (const float4*)xr,
                                                     es, offs, (const float4*)att[l],
                                                     (const float4*)bia[l], houts[l]);
        hin = houts[l];
    }

    // --- pool + BN + FC ---
    hipMemsetAsync(pooled, 0, (size_t)N_GRAPHS * HID * 4, stream);
    pool_kernel<<<SCAN_BLOCKS, 256, 0, stream>>>(hin, batch, pooled);
    final_kernel<<<1, 256, 0, stream>>>(pooled, gamma, beta, fcW, fcb, out);
}

// Round 4
// 521.541 us; speedup vs baseline: 2.8769x; 1.2620x over previous
//
#include <hip/hip_runtime.h>
#include <hip/hip_bf16.h>
#include <math.h>

#define N_NODES 50000
#define N_EDGES 800000
#define N_GRAPHS 64
#define IN_DIM 128
#define HID 64
#define HEADS 4
#define LAT 32
#define SCAN_BLOCKS ((N_NODES + 255) / 256)   // 196

typedef __attribute__((ext_vector_type(8))) short bf16x8;
typedef __attribute__((ext_vector_type(4))) float floatx4;

__device__ inline unsigned short f2bf(float f) {   // RNE
    unsigned u = __float_as_uint(f);
    return (unsigned short)((u + 0x7fffu + ((u >> 16) & 1u)) >> 16);
}

// ---------------------------------------------------------------------------
// Counting-sort of edges by dst: histogram -> hierarchical scan -> scatter
// ---------------------------------------------------------------------------
__global__ __launch_bounds__(256) void deg_kernel(const int* __restrict__ dsts,
                                                  int* __restrict__ cnt, int E) {
    int e = blockIdx.x * 256 + threadIdx.x;
    if (e < E) atomicAdd(&cnt[dsts[e]], 1);
}

__global__ __launch_bounds__(256) void sum_kernel(const int* __restrict__ cnt,
                                                  int* __restrict__ bsum) {
    __shared__ int s[256];
    int i = blockIdx.x * 256 + threadIdx.x;
    s[threadIdx.x] = (i < N_NODES) ? cnt[i] : 0;
    __syncthreads();
    for (int off = 128; off; off >>= 1) {
        if (threadIdx.x < off) s[threadIdx.x] += s[threadIdx.x + off];
        __syncthreads();
    }
    if (threadIdx.x == 0) bsum[blockIdx.x] = s[0];
}

__global__ __launch_bounds__(256) void scan_blocks_kernel(const int* __restrict__ bsum,
                                                          int* __restrict__ boffs,
                                                          int* __restrict__ offs_end) {
    __shared__ int buf[256];
    int t = threadIdx.x;
    int v = (t < SCAN_BLOCKS) ? bsum[t] : 0;
    buf[t] = v;
    __syncthreads();
    #pragma unroll
    for (int off = 1; off < 256; off <<= 1) {
        int tmp = (t >= off) ? buf[t - off] : 0;
        __syncthreads();
        buf[t] += tmp;
        __syncthreads();
    }
    if (t < SCAN_BLOCKS) boffs[t] = buf[t] - v;
    if (t == 255) *offs_end = buf[255];
}

__global__ __launch_bounds__(256) void scan_final_kernel(int* __restrict__ cnt,
                                                         const int* __restrict__ boffs,
                                                         int* __restrict__ offs) {
    __shared__ int buf[256];
    int t = threadIdx.x;
    int i = blockIdx.x * 256 + t;
    int v = (i < N_NODES) ? cnt[i] : 0;
    if (i < N_NODES) cnt[i] = 0;   // zero for reuse as scatter counter
    buf[t] = v;
    __syncthreads();
    #pragma unroll
    for (int off = 1; off < 256; off <<= 1) {
        int tmp = (t >= off) ? buf[t - off] : 0;
        __syncthreads();
        buf[t] += tmp;
        __syncthreads();
    }
    if (i < N_NODES) offs[i] = boffs[blockIdx.x] + buf[t] - v;   // exclusive
}

__global__ __launch_bounds__(256) void scatter_kernel(const int* __restrict__ srcs,
                                                      const int* __restrict__ dsts,
                                                      const int* __restrict__ offs,
                                                      int* __restrict__ cnt,
                                                      int* __restrict__ es, int E) {
    int e = blockIdx.x * 256 + threadIdx.x;
    if (e < E) {
        int d = dsts[e];
        int pos = offs[d] + atomicAdd(&cnt[d], 1);
        es[pos] = srcs[e];
    }
}

// ---------------------------------------------------------------------------
// x (fp32) -> bf16 packed
// ---------------------------------------------------------------------------
__global__ __launch_bounds__(256) void conv_kernel(const float* __restrict__ x,
                                                   unsigned* __restrict__ xbf) {
    int i = blockIdx.x * 256 + threadIdx.x;   // one per 2 elements
    if (i < N_NODES * IN_DIM / 2) {
        float2 v = reinterpret_cast<const float2*>(x)[i];
        xbf[i] = (unsigned)f2bf(v.x) | ((unsigned)f2bf(v.y) << 16);
    }
}

// ---------------------------------------------------------------------------
// Pack Wl|Wr (fp32 [K,256] each) into MFMA B-fragment order, bf16:
// Bpk[((tile*KC + kc)*64 + lane)*8 + j] = W[kc*32+(lane>>4)*8+j][ (tile&15)*16 + (lane&15) ]
// tiles 0..15 -> Wl, 16..31 -> Wr.
// ---------------------------------------------------------------------------
__global__ __launch_bounds__(256) void pack_kernel(const float* __restrict__ Wl,
                                                   const float* __restrict__ Wr,
                                                   int KC,
                                                   unsigned short* __restrict__ Bpk) {
    int idx = blockIdx.x * 256 + threadIdx.x;
    if (idx >= 32 * KC * 512) return;
    int j = idx & 7;
    int lane = (idx >> 3) & 63;
    int rem = idx >> 9;
    int kc = rem % KC;
    int tile = rem / KC;
    int k = kc * 32 + (lane >> 4) * 8 + j;
    int n = (tile & 15) * 16 + (lane & 15);
    const float* W = (tile < 16) ? Wl : Wr;
    Bpk[idx] = f2bf(W[k * 256 + n]);
}

// ---------------------------------------------------------------------------
// MFMA GEMM: [xl|xr][n,512] = Abf[n,K](bf16) @ [Wl|Wr](packed bf16 frags).
// Block = 16 rows x 512 cols, 4 waves x 8 n-tiles of 16.
// A staged to LDS in fragment order (pos = tid*16B): conflict-free b128 ops.
// Epilogue: tiles 0..15 -> xlp (bf16 packed), 16..31 -> xr (fp32).
// ---------------------------------------------------------------------------
template <int K>
__global__ __launch_bounds__(256) void gemm_mfma_kernel(
    const unsigned short* __restrict__ Abf,
    const unsigned short* __restrict__ Bpk,
    unsigned short* __restrict__ xlp,
    float* __restrict__ xr) {
    constexpr int KC = K / 32;
    constexpr int CHUNKS = 16 * K / 8;        // 256 (K=128) or 128 (K=64)
    __shared__ short As[CHUNKS * 8];
    int br = blockIdx.x * 16;                 // 50000 = 16*3125 exactly
    int t = threadIdx.x;
    if (t < CHUNKS) {
        // LDS pos t holds frag chunk (kc = t>>6, quad = (t>>4)&3, row = t&15)
        int row = t & 15;
        int kcol = (t >> 6) * 32 + ((t >> 4) & 3) * 8;
        *reinterpret_cast<uint4*>(&As[t * 8]) =
            *reinterpret_cast<const uint4*>(&Abf[(size_t)(br + row) * K + kcol]);
    }
    __syncthreads();
    int wave = t >> 6, lane = t & 63;
    int quad = lane >> 4, l16 = lane & 15;
    bf16x8 afrag[KC];
    #pragma unroll
    for (int kc = 0; kc < KC; ++kc)
        afrag[kc] = *reinterpret_cast<const bf16x8*>(&As[((kc * 4 + quad) * 16 + l16) * 8]);
    #pragma unroll
    for (int ct = 0; ct < 8; ++ct) {
        int tile = wave * 8 + ct;
        floatx4 acc = {0.f, 0.f, 0.f, 0.f};
        #pragma unroll
        for (int kc = 0; kc < KC; ++kc) {
            bf16x8 bfrag = *reinterpret_cast<const bf16x8*>(
                &Bpk[(size_t)((tile * KC + kc) * 64 + lane) * 8]);
            acc = __builtin_amdgcn_mfma_f32_16x16x32_bf16(afrag[kc], bfrag, acc, 0, 0, 0);
        }
        // C/D layout: col = lane&15, row = quad*4 + reg
        if (tile < 16) {
            int col = tile * 16 + l16;
            #pragma unroll
            for (int r = 0; r < 4; ++r)
                xlp[(size_t)(br + quad * 4 + r) * 256 + col] = f2bf(acc[r]);
        } else {
            int col = (tile - 16) * 16 + l16;
            #pragma unroll
            for (int r = 0; r < 4; ++r)
                xr[(size_t)(br + quad * 4 + r) * 256 + col] = acc[r];
        }
    }
}

// ---------------------------------------------------------------------------
// Attention: ONE 64-lane wave per node (4 nodes / 256-block).
// lane = h*16 + dq : head h, dims 4*dq..4*dq+3. Outputs: fp32 h (if hout)
// and/or packed bf16 h (if hbf, feeds next layer's MFMA GEMM).
// ---------------------------------------------------------------------------
__global__ __launch_bounds__(256) void attn_kernel(const uint2* __restrict__ xlp,
                                                   const float4* __restrict__ xr4,
                                                   const int* __restrict__ es,
                                                   const int* __restrict__ offs,
                                                   const float4* __restrict__ att4,
                                                   const float4* __restrict__ bias4,
                                                   float* __restrict__ hout,
                                                   unsigned* __restrict__ hbf) {
    int node = blockIdx.x * 4 + (threadIdx.x >> 6);
    int lane = threadIdx.x & 63;
    int beg = offs[node], end = offs[node + 1];
    float4 xr_v = xr4[(size_t)node * 64 + lane];
    float4 att_v = att4[lane];
    float m = -INFINITY, l = 0.f;
    float a0 = 0.f, a1 = 0.f, a2 = 0.f, a3 = 0.f;

    for (int cb = beg; cb < end; cb += 64) {
        int nch = min(64, end - cb);
        int eidx = (lane < nch) ? es[cb + lane] : 0;
        int j = 0;
        for (; j + 2 <= nch; j += 2) {
            int s0 = __shfl(eidx, j);
            int s1 = __shfl(eidx, j + 1);
            uint2 v0 = xlp[(size_t)s0 * 64 + lane];
            uint2 v1 = xlp[(size_t)s1 * 64 + lane];
            float x00 = __uint_as_float(v0.x << 16);
            float x01 = __uint_as_float(v0.x & 0xffff0000u);
            float x02 = __uint_as_float(v0.y << 16);
            float x03 = __uint_as_float(v0.y & 0xffff0000u);
            float x10 = __uint_as_float(v1.x << 16);
            float x11 = __uint_as_float(v1.x & 0xffff0000u);
            float x12 = __uint_as_float(v1.y << 16);
            float x13 = __uint_as_float(v1.y & 0xffff0000u);
            float e;
            e = x00 + xr_v.x; e = (e > 0.f) ? e : 0.2f * e; float z0 = e * att_v.x;
            e = x10 + xr_v.x; e = (e > 0.f) ? e : 0.2f * e; float z1 = e * att_v.x;
            e = x01 + xr_v.y; e = (e > 0.f) ? e : 0.2f * e; z0 = fmaf(e, att_v.y, z0);
            e = x11 + xr_v.y; e = (e > 0.f) ? e : 0.2f * e; z1 = fmaf(e, att_v.y, z1);
            e = x02 + xr_v.z; e = (e > 0.f) ? e : 0.2f * e; z0 = fmaf(e, att_v.z, z0);
            e = x12 + xr_v.z; e = (e > 0.f) ? e : 0.2f * e; z1 = fmaf(e, att_v.z, z1);
            e = x03 + xr_v.w; e = (e > 0.f) ? e : 0.2f * e; z0 = fmaf(e, att_v.w, z0);
            e = x13 + xr_v.w; e = (e > 0.f) ? e : 0.2f * e; z1 = fmaf(e, att_v.w, z1);
            z0 += __shfl_xor(z0, 8);  z1 += __shfl_xor(z1, 8);
            z0 += __shfl_xor(z0, 4);  z1 += __shfl_xor(z1, 4);
            z0 += __shfl_xor(z0, 2);  z1 += __shfl_xor(z1, 2);
            z0 += __shfl_xor(z0, 1);  z1 += __shfl_xor(z1, 1);
            float mn = fmaxf(m, fmaxf(z0, z1));
            float sc = __expf(m - mn);       // first pair: exp(-inf)=0
            float p0 = __expf(z0 - mn);
            float p1 = __expf(z1 - mn);
            a0 = a0 * sc + p0 * x00 + p1 * x10;
            a1 = a1 * sc + p0 * x01 + p1 * x11;
            a2 = a2 * sc + p0 * x02 + p1 * x12;
            a3 = a3 * sc + p0 * x03 + p1 * x13;
            l = l * sc + p0 + p1;
            m = mn;
        }
        if (j < nch) {   // odd tail edge
            int s0 = __shfl(eidx, j);
            uint2 v0 = xlp[(size_t)s0 * 64 + lane];
            float x00 = __uint_as_float(v0.x << 16);
            float x01 = __uint_as_float(v0.x & 0xffff0000u);
            float x02 = __uint_as_float(v0.y << 16);
            float x03 = __uint_as_float(v0.y & 0xffff0000u);
            float e;
            e = x00 + xr_v.x; e = (e > 0.f) ? e : 0.2f * e; float z0 = e * att_v.x;
            e = x01 + xr_v.y; e = (e > 0.f) ? e : 0.2f * e; z0 = fmaf(e, att_v.y, z0);
            e = x02 + xr_v.z; e = (e > 0.f) ? e : 0.2f * e; z0 = fmaf(e, att_v.z, z0);
            e = x03 + xr_v.w; e = (e > 0.f) ? e : 0.2f * e; z0 = fmaf(e, att_v.w, z0);
            z0 += __shfl_xor(z0, 8);
            z0 += __shfl_xor(z0, 4);
            z0 += __shfl_xor(z0, 2);
            z0 += __shfl_xor(z0, 1);
            float mn = fmaxf(m, z0);
            float sc = __expf(m - mn);
            float p0 = __expf(z0 - mn);
            a0 = a0 * sc + p0 * x00;
            a1 = a1 * sc + p0 * x01;
            a2 = a2 * sc + p0 * x02;
            a3 = a3 * sc + p0 * x03;
            l = l * sc + p0;
            m = mn;
        }
    }
    float inv = 1.f / (l + 1e-16f);
    a0 *= inv; a1 *= inv; a2 *= inv; a3 *= inv;
    // mean over heads: lanes h*16+dq -> sum across h via xor 16, 32
    a0 += __shfl_xor(a0, 16); a0 += __shfl_xor(a0, 32);
    a1 += __shfl_xor(a1, 16); a1 += __shfl_xor(a1, 32);
    a2 += __shfl_xor(a2, 16); a2 += __shfl_xor(a2, 32);
    a3 += __shfl_xor(a3, 16); a3 += __shfl_xor(a3, 32);
    if (lane < 16) {
        float4 bv = bias4[lane];
        float4 o;
        o.x = 0.25f * a0 + bv.x; o.x = (o.x > 0.f) ? o.x : 0.1f * o.x;
        o.y = 0.25f * a1 + bv.y; o.y = (o.y > 0.f) ? o.y : 0.1f * o.y;
        o.z = 0.25f * a2 + bv.z; o.z = (o.z > 0.f) ? o.z : 0.1f * o.z;
        o.w = 0.25f * a3 + bv.w; o.w = (o.w > 0.f) ? o.w : 0.1f * o.w;
        if (hout)
            *reinterpret_cast<float4*>(&hout[(size_t)node * HID + lane * 4]) = o;
        if (hbf) {
            uint2 pk;
            pk.x = (unsigned)f2bf(o.x) | ((unsigned)f2bf(o.y) << 16);
            pk.y = (unsigned)f2bf(o.z) | ((unsigned)f2bf(o.w) << 16);
            *reinterpret_cast<uint2*>(&hbf[(size_t)node * 32 + lane * 2]) = pk;
        }
    }
}

// ---------------------------------------------------------------------------
// Pool: batch sorted -> accumulate runs locally, flush on graph change.
// ---------------------------------------------------------------------------
__global__ __launch_bounds__(256) void pool_kernel(const float* __restrict__ hfin,
                                                   const int* __restrict__ batch,
                                                   float* __restrict__ pooled) {
    int base = blockIdx.x * 256;
    int g = threadIdx.x >> 6, lane = threadIdx.x & 63;
    int lim = min(base + 256, N_NODES);
    int cur = -1;
    float s = 0.f;
    for (int i = base + g; i < lim; i += 4) {
        int b = batch[i];
        if (b != cur) {
            if (cur >= 0) atomicAdd(&pooled[cur * HID + lane], s);
            cur = b; s = 0.f;
        }
        s += hfin[(size_t)i * HID + lane];
    }
    if (cur >= 0) atomicAdd(&pooled[cur * HID + lane], s);
}

// ---------------------------------------------------------------------------
// BN over graphs (biased var) + FC. Single block.
// ---------------------------------------------------------------------------
__global__ __launch_bounds__(256) void final_kernel(const float* __restrict__ pooled,
                                                    const float* __restrict__ gamma,
                                                    const float* __restrict__ beta,
                                                    const float* __restrict__ fcW,
                                                    const float* __restrict__ fcb,
                                                    float* __restrict__ out) {
    __shared__ float P[N_GRAPHS * HID];
    __shared__ float normS[N_GRAPHS * HID];
    __shared__ float meanS[HID], rstdS[HID];
    int t = threadIdx.x;
    for (int i = t; i < N_GRAPHS * HID; i += 256) P[i] = pooled[i];
    __syncthreads();
    if (t < HID) {
        float s = 0.f;
        for (int g = 0; g < N_GRAPHS; ++g) s += P[g * HID + t];
        float mean = s / (float)N_GRAPHS;
        float v = 0.f;
        for (int g = 0; g < N_GRAPHS; ++g) {
            float dd = P[g * HID + t] - mean;
            v += dd * dd;
        }
        v /= (float)N_GRAPHS;
        meanS[t] = mean;
        rstdS[t] = rsqrtf(v + 1e-5f);
    }
    __syncthreads();
    for (int i = t; i < N_GRAPHS * HID; i += 256) {
        int d = i & 63;
        normS[i] = (P[i] - meanS[d]) * rstdS[d] * gamma[d] + beta[d];
    }
    __syncthreads();
    for (int i = t; i < N_GRAPHS * LAT; i += 256) {
        int g = i >> 5, lat = i & 31;
        float s = fcb[lat];
        for (int d = 0; d < HID; ++d) s += normS[g * HID + d] * fcW[lat * HID + d];
        out[i] = s;
    }
}

// ---------------------------------------------------------------------------
extern "C" void kernel_launch(void* const* d_in, const int* in_sizes, int n_in,
                              void* d_out, int out_size, void* d_ws, size_t ws_size,
                              hipStream_t stream) {
    const float* x      = (const float*)d_in[0];
    const int*   ei     = (const int*)d_in[1];
    const int*   batch  = (const int*)d_in[2];
    const float* Wl[3]  = {(const float*)d_in[3], (const float*)d_in[7],  (const float*)d_in[11]};
    const float* Wr[3]  = {(const float*)d_in[4], (const float*)d_in[8],  (const float*)d_in[12]};
    const float* att[3] = {(const float*)d_in[5], (const float*)d_in[9],  (const float*)d_in[13]};
    const float* bia[3] = {(const float*)d_in[6], (const float*)d_in[10], (const float*)d_in[14]};
    const float* gamma  = (const float*)d_in[15];
    const float* beta   = (const float*)d_in[16];
    const float* fcW    = (const float*)d_in[17];
    const float* fcb    = (const float*)d_in[18];
    float* out = (float*)d_out;

    char* p = (char*)d_ws;
    auto alloc = [&](size_t bytes) {
        char* r = p;
        p += (bytes + 255) & ~(size_t)255;
        return r;
    };
    unsigned* xbf   = (unsigned*)alloc((size_t)N_NODES * IN_DIM * 2);   // bf16 x; reused as hfin
    unsigned short* xlp = (unsigned short*)alloc((size_t)N_NODES * 256 * 2);
    float* xr       = (float*)alloc((size_t)N_NODES * 256 * 4);
    unsigned* hbf0  = (unsigned*)alloc((size_t)N_NODES * HID * 2);
    unsigned* hbf1  = (unsigned*)alloc((size_t)N_NODES * HID * 2);
    unsigned short* Bpk0 = (unsigned short*)alloc(32 * 4 * 512 * 2);
    unsigned short* Bpk1 = (unsigned short*)alloc(32 * 2 * 512 * 2);
    unsigned short* Bpk2 = (unsigned short*)alloc(32 * 2 * 512 * 2);
    int*   es      = (int*)alloc((size_t)N_EDGES * 4);
    int*   offs    = (int*)alloc((size_t)(N_NODES + 1) * 4);
    int*   cnt     = (int*)alloc((size_t)N_NODES * 4);
    int*   bsum    = (int*)alloc((size_t)SCAN_BLOCKS * 4);
    int*   boffs   = (int*)alloc((size_t)SCAN_BLOCKS * 4);
    float* pooled  = (float*)alloc((size_t)N_GRAPHS * HID * 4);
    float* hfin    = (float*)xbf;   // alias: xbf dead after layer-0 GEMM

    const int* srcs = ei;
    const int* dsts = ei + N_EDGES;

    // --- preprocessing: x->bf16, pack weights to fragment order ---
    conv_kernel<<<(N_NODES * IN_DIM / 2 + 255) / 256, 256, 0, stream>>>(x, xbf);
    pack_kernel<<<256, 256, 0, stream>>>(Wl[0], Wr[0], 4, Bpk0);
    pack_kernel<<<128, 256, 0, stream>>>(Wl[1], Wr[1], 2, Bpk1);
    pack_kernel<<<128, 256, 0, stream>>>(Wl[2], Wr[2], 2, Bpk2);

    // --- sort edges by dst (counting sort, hierarchical scan) ---
    hipMemsetAsync(cnt, 0, (size_t)N_NODES * 4, stream);
    int eb = (N_EDGES + 255) / 256;
    deg_kernel<<<eb, 256, 0, stream>>>(dsts, cnt, N_EDGES);
    sum_kernel<<<SCAN_BLOCKS, 256, 0, stream>>>(cnt, bsum);
    scan_blocks_kernel<<<1, 256, 0, stream>>>(bsum, boffs, &offs[N_NODES]);
    scan_final_kernel<<<SCAN_BLOCKS, 256, 0, stream>>>(cnt, boffs, offs);
    scatter_kernel<<<eb, 256, 0, stream>>>(srcs, dsts, offs, cnt, es, N_EDGES);

    // --- 3 GATv2 layers (GEMM on matrix cores, bf16 in / fp32 acc) ---
    int gb = N_NODES / 16;   // 3125
    // layer 0
    gemm_mfma_kernel<IN_DIM><<<gb, 256, 0, stream>>>((const unsigned short*)xbf, Bpk0, xlp, xr);
    attn_kernel<<<N_NODES / 4, 256, 0, stream>>>((const uint2*)xlp, (const float4*)xr,
                                                 es, offs, (const float4*)att[0],
                                                 (const float4*)bia[0], nullptr, hbf0);
    // layer 1
    gemm_mfma_kernel<HID><<<gb, 256, 0, stream>>>((const unsigned short*)hbf0, Bpk1, xlp, xr);
    attn_kernel<<<N_NODES / 4, 256, 0, stream>>>((const uint2*)xlp, (const float4*)xr,
                                                 es, offs, (const float4*)att[1],
                                                 (const float4*)bia[1], nullptr, hbf1);
    // layer 2
    gemm_mfma_kernel<HID><<<gb, 256, 0, stream>>>((const unsigned short*)hbf1, Bpk2, xlp, xr);
    attn_kernel<<<N_NODES / 4, 256, 0, stream>>>((const uint2*)xlp, (const float4*)xr,
                                                 es, offs, (const float4*)att[2],
                                                 (const float4*)bia[2], hfin, nullptr);

    // --- pool + BN + FC ---
    hipMemsetAsync(pooled, 0, (size_t)N_GRAPHS * HID * 4, stream);
    pool_kernel<<<SCAN_BLOCKS, 256, 0, stream>>>(hfin, batch, pooled);
    final_kernel<<<1, 256, 0, stream>>>(pooled, gamma, beta, fcW, fcb, out);
}